// Round 5
// baseline (127.970 us; speedup 1.0000x reference)
//
#include <hip/hip_runtime.h>
#include <hip/hip_bf16.h>

// LowRankBilinearPooling: out[b,o] = (sum_i relu(x1 W1))_h * (sum_j relu(x2 W2))_h @ Wp + bp*196^2
// B=16, N=196, C=768, H=512, O=128. fp32 in/out; bf16 MFMA inside.
// 2 dispatches: w_tile (W -> bf16 gemm-LDS order, zero counters) ->
// gemm+relu+rowsum with per-batch last-block fused projection.

#define NB 16
#define NROW 196
#define KC_ 768
#define HH 512
#define OO 128

using short4v = __attribute__((ext_vector_type(4))) short;
using short8 = __attribute__((ext_vector_type(8))) short;
using f32x16 = __attribute__((ext_vector_type(16))) float;

__device__ __forceinline__ short2 pk2bf(float a, float b) {
    // v_cvt_pk_bf16_f32 on gfx950
    __hip_bfloat162 h = __float22bfloat162_rn(make_float2(a, b));
    union { __hip_bfloat162 h; short2 s; } u; u.h = h;
    return u.s;
}

// Prepass: tile+convert W1/W2 into the gemm's exact LDS byte order, bf16.
// Wt plane (branch*4+ht)*12+kc, unit (p,col) = bf16 of
//   W[(kc*64+p*8+j)*512 + ht*128 + col], j=0..7.  96 blocks x 256 threads.
// Block 0 also zeroes the 16 per-batch completion counters.
__global__ __launch_bounds__(256)
void w_tile(const float* __restrict__ W1, const float* __restrict__ W2,
            unsigned short* __restrict__ Wt, int* __restrict__ cnt) {
    const int t = threadIdx.x;
    if (blockIdx.x == 0 && t < NB) cnt[t] = 0;
    const int bb = blockIdx.x;              // branch*48 + ht*12 + kc
    const int branch = bb / 48;
    const int rem = bb % 48;
    const int ht = rem / 12;
    const int kc = rem % 12;
    const float* __restrict__ W = branch ? W2 : W1;
    unsigned short* __restrict__ out = Wt + (size_t)bb * 8192;
#pragma unroll
    for (int i = 0; i < 4; ++i) {
        const int u = i * 256 + t;
        const int p = u >> 7, col = u & 127;
        const float* src = W + (kc * 64 + p * 8) * HH + ht * 128 + col;
        float f[8];
#pragma unroll
        for (int j = 0; j < 8; ++j) f[j] = src[j * HH];   // lanes walk col: coalesced
        short8 v; short2 s;
#pragma unroll
        for (int j = 0; j < 4; ++j) {
            s = pk2bf(f[2 * j], f[2 * j + 1]); v[2 * j] = s.x; v[2 * j + 1] = s.y;
        }
        *(short8*)(out + u * 8) = v;
    }
}

// Kernel 1: fused GEMM + relu + row-sum + (per-batch last block) projection.
// Grid: 256 blocks = 2(branch) x 16(b) x 4(ht) x 2(mh). Block: 512 thr = 8 waves
// = (mp 0..3: 32-row tile) x (sp 0..1: 64-col strip). K chunked by 64,
// double-buffered LDS (plane stride 129 pad), one barrier per chunk,
// register-staged prefetch distance 2.
__global__ __launch_bounds__(512, 1)
void gemm_relu_rowsum_proj(const float* __restrict__ x1, const float* __restrict__ x2,
                           const unsigned short* __restrict__ Wt,
                           float* __restrict__ sbuf, int* __restrict__ cnt,
                           const float* __restrict__ Wp, const float* __restrict__ bp,
                           float* __restrict__ out) {
    __shared__ unsigned short Alds[2][8 * 129 * 8];
    __shared__ unsigned short Blds[2][8 * 129 * 8];
    __shared__ float psum[16 * 32];
    __shared__ float spl[HH];
    __shared__ float red[4][OO];
    __shared__ int lastflag;

    const int bid = blockIdx.x;
    const int p  = bid & 31;           // (branch,b): tiles of same x[b] share an XCD
    const int tt = bid >> 5;
    const int branch = p >> 4;
    const int b      = p & 15;
    const int ht = tt >> 1;
    const int mh = tt & 1;

    const float* __restrict__ x = branch ? x2 : x1;
    const unsigned short* __restrict__ Wtb = Wt + (size_t)((branch * 4 + ht) * 12) * 8192;

    const int t   = threadIdx.x;
    const int l16 = t & 15;            // A: 16B slot within a row's 256B chunk-span
    const int rg  = t >> 4;            // A: row group 0..31 (row = rg + 32*r)
    const float* xbase = x + (b * NROW + mh * 128) * KC_ + l16 * 4;

    const int bp0 = t >> 7,          bc0 = t & 127;          // B unit t
    const int bp1 = (t + 512) >> 7,  bc1 = t & 127;          // B unit t+512

    float4 av[4];
    short8 bva, bvb;

    auto load_stage = [&](int kc) {
#pragma unroll
        for (int r = 0; r < 4; ++r) {
            const int row = rg + 32 * r;
            if (mh * 128 + row < NROW)
                av[r] = *(const float4*)(xbase + row * KC_ + kc * 64);
            else
                av[r] = make_float4(0.f, 0.f, 0.f, 0.f);
        }
        const unsigned short* wc = Wtb + kc * 8192;
        bva = *(const short8*)(wc + bp0 * 1024 + bc0 * 8);
        bvb = *(const short8*)(wc + bp1 * 1024 + bc1 * 8);
    };

    auto write_stage = [&](int buf) {
#pragma unroll
        for (int r = 0; r < 4; ++r) {
            short4v sv; short2 s;
            s = pk2bf(av[r].x, av[r].y); sv[0] = s.x; sv[1] = s.y;
            s = pk2bf(av[r].z, av[r].w); sv[2] = s.x; sv[3] = s.y;
            const int row = rg + 32 * r;
            *(short4v*)&Alds[buf][((l16 >> 1) * 129 + row) * 8 + (l16 & 1) * 4] = sv;
        }
        *(short8*)&Blds[buf][(bp0 * 129 + bc0) * 8] = bva;
        *(short8*)&Blds[buf][(bp1 * 129 + bc1) * 8] = bvb;
    };

    const int w  = t >> 6;
    const int l  = t & 63;
    const int m  = l & 31;
    const int q  = l >> 5;
    const int sp = w & 1;              // 64-col strip
    const int mp = w >> 1;             // 32-row tile
    const int aoff = (mp * 32 + m) * 8;
    const int boff = (sp * 64 + m) * 8;

    f32x16 acc0 = {}, acc1 = {};

    load_stage(0);
    write_stage(0);
    load_stage(1);
    __syncthreads();

#pragma unroll 1
    for (int kc = 0; kc < 12; ++kc) {
        const int pb = kc & 1;
#pragma unroll
        for (int ks = 0; ks < 4; ++ks) {
            const int base = (ks * 2 + q) * 129 * 8;
            short8 af = *(const short8*)&Alds[pb][base + aoff];
            short8 b0 = *(const short8*)&Blds[pb][base + boff];
            short8 b1 = *(const short8*)&Blds[pb][base + boff + 256];
            acc0 = __builtin_amdgcn_mfma_f32_32x32x16_bf16(af, b0, acc0, 0, 0, 0);
            acc1 = __builtin_amdgcn_mfma_f32_32x32x16_bf16(af, b1, acc1, 0, 0, 0);
        }
        if (kc < 11) write_stage(1 - pb);   // chunk kc+1 -> other buffer
        if (kc < 10) load_stage(kc + 2);    // regs: stays in flight across barrier
        __syncthreads();                    // one barrier per chunk
    }

    // relu + sum over rows. C layout: col = lane&31 (m101); lanes l and l^32's
    // 16 regs together cover all 32 rows, order irrelevant for a sum.
    float cs0 = 0.f, cs1 = 0.f;
#pragma unroll
    for (int r = 0; r < 16; ++r) {
        cs0 += fmaxf(acc0[r], 0.f);
        cs1 += fmaxf(acc1[r], 0.f);
    }
    cs0 += __shfl_xor(cs0, 32);
    cs1 += __shfl_xor(cs1, 32);
    if (l < 32) {
        psum[((sp * 2 + 0) * 4 + mp) * 32 + l] = cs0;  // col tile 2sp
        psum[((sp * 2 + 1) * 4 + mp) * 32 + l] = cs1;  // col tile 2sp+1
    }
    __syncthreads();
    if (t < 128) {
        const int ct = t >> 5;
        const int cl = t & 31;
        float v = 0.f;
#pragma unroll
        for (int mp2 = 0; mp2 < 4; ++mp2)
            v += psum[(ct * 4 + mp2) * 32 + cl];
        sbuf[((branch * 2 + mh) * NB + b) * HH + ht * 128 + t] = v;
    }

    // --- per-batch completion: 16 blocks share batch b; last one projects ---
    __threadfence();                   // release this thread's sbuf stores (device scope)
    __syncthreads();                   // all fences in this block retired
    if (t == 0) {
        int old = atomicAdd(&cnt[b], 1);   // device-scope (m20)
        lastflag = (old == NB - 1);
    }
    __syncthreads();
    if (!lastflag) return;
    __threadfence();                   // acquire: see all 16 blocks' sbuf

    // Projection for batch b — numerically identical to the R3 proj_kernel.
    {
        const float s1 = sbuf[(0 * NB + b) * HH + t] + sbuf[(1 * NB + b) * HH + t];
        const float s2 = sbuf[(2 * NB + b) * HH + t] + sbuf[(3 * NB + b) * HH + t];
        spl[t] = s1 * s2;
    }
    __syncthreads();
    const int to = t & 127, hq = t >> 7;
    float acc = 0.f;
#pragma unroll 8
    for (int h = hq * 128; h < hq * 128 + 128; ++h)
        acc += spl[h] * Wp[h * OO + to];
    red[hq][to] = acc;
    __syncthreads();
    if (t < OO)
        out[b * OO + t] = red[0][t] + red[1][t] + red[2][t] + red[3][t]
                        + bp[t] * 38416.0f;   // 196*196
}

extern "C" void kernel_launch(void* const* d_in, const int* in_sizes, int n_in,
                              void* d_out, int out_size, void* d_ws, size_t ws_size,
                              hipStream_t stream) {
    const float* x1 = (const float*)d_in[0];
    const float* x2 = (const float*)d_in[1];
    const float* W1 = (const float*)d_in[2];
    const float* W2 = (const float*)d_in[3];
    const float* Wp = (const float*)d_in[4];
    const float* bp = (const float*)d_in[5];
    float* sbuf = (float*)d_ws;                                    // 128 KB
    unsigned short* Wt = (unsigned short*)((char*)d_ws + 131072);  // 1.5 MB
    int* cnt = (int*)((char*)d_ws + 131072 + 1572864);             // 16 ints

    w_tile<<<96, 256, 0, stream>>>(W1, W2, Wt, cnt);
    gemm_relu_rowsum_proj<<<256, 512, 0, stream>>>(x1, x2, Wt, sbuf, cnt,
                                                   Wp, bp, (float*)d_out);
}

// Round 7
// 95.116 us; speedup vs baseline: 1.3454x; 1.3454x over previous
//
#include <hip/hip_runtime.h>
#include <hip/hip_bf16.h>

// LowRankBilinearPooling: out[b,o] = (sum_i relu(x1 W1))_h * (sum_j relu(x2 W2))_h @ Wp + bp*196^2
// B=16, N=196, C=768, H=512, O=128. fp32 in/out; bf16 MFMA inside.
// 3 dispatches: w_tile -> gemm+relu+rowsum (M-split, 2 blocks/CU) -> proj.
// NOTE: K must NOT be split across blocks (relu sits between K-sum and row-sum).

#define NB 16
#define NROW 196
#define KC_ 768
#define HH 512
#define OO 128

using short8 = __attribute__((ext_vector_type(8))) short;
using f32x16 = __attribute__((ext_vector_type(16))) float;

__device__ __forceinline__ short2 pk2bf(float a, float b) {
    // v_cvt_pk_bf16_f32 on gfx950
    __hip_bfloat162 h = __float22bfloat162_rn(make_float2(a, b));
    union { __hip_bfloat162 h; short2 s; } u; u.h = h;
    return u.s;
}

// Prepass: tile+convert W1/W2 into the gemm's exact LDS byte order, bf16.
// Wt plane (branch*4+ht)*12+kc, unit (p,col) = bf16 of
//   W[(kc*64+p*8+j)*512 + ht*128 + col], j=0..7.  96 blocks x 256 threads.
__global__ __launch_bounds__(256)
void w_tile(const float* __restrict__ W1, const float* __restrict__ W2,
            unsigned short* __restrict__ Wt) {
    const int t = threadIdx.x;
    const int bb = blockIdx.x;              // branch*48 + ht*12 + kc
    const int branch = bb / 48;
    const int rem = bb % 48;
    const int ht = rem / 12;
    const int kc = rem % 12;
    const float* __restrict__ W = branch ? W2 : W1;
    unsigned short* __restrict__ out = Wt + (size_t)bb * 8192;
#pragma unroll
    for (int i = 0; i < 4; ++i) {
        const int u = i * 256 + t;
        const int p = u >> 7, col = u & 127;
        const float* src = W + (kc * 64 + p * 8) * HH + ht * 128 + col;
        float f[8];
#pragma unroll
        for (int j = 0; j < 8; ++j) f[j] = src[j * HH];   // lanes walk col: coalesced
        short8 v; short2 s;
#pragma unroll
        for (int j = 0; j < 4; ++j) {
            s = pk2bf(f[2 * j], f[2 * j + 1]); v[2 * j] = s.x; v[2 * j + 1] = s.y;
        }
        *(short8*)(out + u * 8) = v;
    }
}

// Kernel 1: fused GEMM + relu + row-sum, M-split for 2 blocks/CU.
// Grid: 512 blocks = 2(branch) x 16(b) [low 5 bits: XCD-shared] x 4(ht) x 4(mq).
// Block: 256 thr = 4 waves = (mp 0..1: 32-row tile) x (sp 0..1: 64-col strip),
// 2 accumulators per wave. Tile: 64 rows x 128 cols, FULL K=768 per block.
// K chunked by 64, double-buffered LDS, one barrier per chunk, prefetch dist 2.
__global__ __launch_bounds__(256, 2)
void gemm_relu_rowsum(const float* __restrict__ x1, const float* __restrict__ x2,
                      const unsigned short* __restrict__ Wt,
                      float* __restrict__ sbuf) {
    __shared__ unsigned short Alds[2][8 * 64 * 8];    //  8 KB per buf
    __shared__ unsigned short Blds[2][8 * 128 * 8];   // 16 KB per buf
    __shared__ float psum[8 * 32];

    const int bid = blockIdx.x;
    const int p  = bid & 31;           // (branch,b): all 16 tiles of x[b] share an XCD
    const int tt = bid >> 5;           // 0..15
    const int branch = p >> 4;
    const int b      = p & 15;
    const int ht = tt >> 2;            // 0..3: 128-col tile
    const int mq = tt & 3;             // 0..3: 64-row quarter

    const float* __restrict__ x = branch ? x2 : x1;
    const unsigned short* __restrict__ Wtb = Wt + (size_t)((branch * 4 + ht) * 12) * 8192;

    const int t    = threadIdx.x;
    const int row  = t >> 2;           // A row 0..63
    const int slot = t & 3;            // 16-k slot within 64-k chunk
    const int r_abs = mq * 64 + row;
    const bool valid = r_abs < NROW;
    const float* xrow = x + (b * NROW + (valid ? r_abs : 0)) * KC_ + slot * 16;

    float4 av[4];      // one row's 16 k fp32
    short8 bv[4];      // 4 B units

    auto load_stage = [&](int kc) {
        if (valid) {
#pragma unroll
            for (int i = 0; i < 4; ++i)
                av[i] = *(const float4*)(xrow + kc * 64 + 4 * i);
        } else {
#pragma unroll
            for (int i = 0; i < 4; ++i) av[i] = make_float4(0.f, 0.f, 0.f, 0.f);
        }
        const unsigned short* wc = Wtb + kc * 8192;
#pragma unroll
        for (int i = 0; i < 4; ++i)
            bv[i] = *(const short8*)(wc + (t + 256 * i) * 8);
    };

    auto write_stage = [&](int buf) {
        short8 v0, v1; short2 s;
        s = pk2bf(av[0].x, av[0].y); v0[0] = s.x; v0[1] = s.y;
        s = pk2bf(av[0].z, av[0].w); v0[2] = s.x; v0[3] = s.y;
        s = pk2bf(av[1].x, av[1].y); v0[4] = s.x; v0[5] = s.y;
        s = pk2bf(av[1].z, av[1].w); v0[6] = s.x; v0[7] = s.y;
        s = pk2bf(av[2].x, av[2].y); v1[0] = s.x; v1[1] = s.y;
        s = pk2bf(av[2].z, av[2].w); v1[2] = s.x; v1[3] = s.y;
        s = pk2bf(av[3].x, av[3].y); v1[4] = s.x; v1[5] = s.y;
        s = pk2bf(av[3].z, av[3].w); v1[6] = s.x; v1[7] = s.y;
        *(short8*)&Alds[buf][((slot * 2 + 0) * 64 + row) * 8] = v0;  // k8 grp 2*slot
        *(short8*)&Alds[buf][((slot * 2 + 1) * 64 + row) * 8] = v1;  // k8 grp 2*slot+1
#pragma unroll
        for (int i = 0; i < 4; ++i)
            *(short8*)&Blds[buf][(t + 256 * i) * 8] = bv[i];         // lane-contiguous
    };

    const int w  = t >> 6;             // wave 0..3
    const int l  = t & 63;
    const int m  = l & 31;
    const int q  = l >> 5;
    const int sp = w & 1;              // 64-col strip
    const int mp = w >> 1;             // 32-row tile
    const int aoff = (mp * 32 + m) * 8;
    const int boff = (sp * 64 + m) * 8;

    f32x16 acc0 = {}, acc1 = {};

    load_stage(0);
    write_stage(0);
    load_stage(1);
    __syncthreads();

#pragma unroll 1
    for (int kc = 0; kc < 12; ++kc) {
        const int pb = kc & 1;
#pragma unroll
        for (int ks = 0; ks < 4; ++ks) {
            const int kp = ks * 2 + q;
            short8 af = *(const short8*)&Alds[pb][kp * 512 + aoff];
            short8 b0 = *(const short8*)&Blds[pb][kp * 1024 + boff];
            short8 b1 = *(const short8*)&Blds[pb][kp * 1024 + boff + 256];
            acc0 = __builtin_amdgcn_mfma_f32_32x32x16_bf16(af, b0, acc0, 0, 0, 0);
            acc1 = __builtin_amdgcn_mfma_f32_32x32x16_bf16(af, b1, acc1, 0, 0, 0);
        }
        if (kc < 11) write_stage(1 - pb);   // chunk kc+1 -> other buffer
        if (kc < 10) load_stage(kc + 2);    // regs: stays in flight across barrier
        __syncthreads();                    // one barrier per chunk
    }

    // relu + sum over rows (AFTER full-K accumulation — the only legal place).
    // C layout: col = lane&31 (m101); lanes l and l^32 together cover all 32 rows.
    float cs0 = 0.f, cs1 = 0.f;
#pragma unroll
    for (int r = 0; r < 16; ++r) {
        cs0 += fmaxf(acc0[r], 0.f);
        cs1 += fmaxf(acc1[r], 0.f);
    }
    cs0 += __shfl_xor(cs0, 32);
    cs1 += __shfl_xor(cs1, 32);
    if (l < 32) {
        psum[((sp * 2 + 0) * 2 + mp) * 32 + l] = cs0;  // strip sp*2:   cols sp*64+0..31
        psum[((sp * 2 + 1) * 2 + mp) * 32 + l] = cs1;  // strip sp*2+1: cols sp*64+32..63
    }
    __syncthreads();
    if (t < 128) {
        const int ct = t >> 5;             // strip 0..3
        const int cl = t & 31;
        const float v = psum[(ct * 2 + 0) * 32 + cl] + psum[(ct * 2 + 1) * 32 + cl];
        // plane = branch*4 + mq : branch-0 planes 0..3, branch-1 planes 4..7
        sbuf[((branch * 4 + mq) * NB + b) * HH + ht * 128 + t] = v;
    }
}

// Kernel 2: out[b,o] = sum_h (s1[b,h]*s2[b,h]) * Wp[h,o] + bp[o]*196^2
// s1 = planes 0..3 summed, s2 = planes 4..7 summed (mq partials, each relu'd full-K).
__global__ __launch_bounds__(512)
void proj_kernel(const float* __restrict__ sbuf, const float* __restrict__ Wp,
                 const float* __restrict__ bp, float* __restrict__ out) {
    __shared__ float spl[HH];
    __shared__ float red[4][OO];
    const int b = blockIdx.x, t = threadIdx.x;
    {
        float s1 = 0.f, s2 = 0.f;
#pragma unroll
        for (int i = 0; i < 4; ++i) {
            s1 += sbuf[((0 + i) * NB + b) * HH + t];
            s2 += sbuf[((4 + i) * NB + b) * HH + t];
        }
        spl[t] = s1 * s2;
    }
    __syncthreads();
    const int to = t & 127, hq = t >> 7;
    float acc = 0.f;
#pragma unroll 8
    for (int h = hq * 128; h < hq * 128 + 128; ++h)
        acc += spl[h] * Wp[h * OO + to];
    red[hq][to] = acc;
    __syncthreads();
    if (t < OO)
        out[b * OO + t] = red[0][t] + red[1][t] + red[2][t] + red[3][t]
                        + bp[t] * 38416.0f;   // 196*196
}

extern "C" void kernel_launch(void* const* d_in, const int* in_sizes, int n_in,
                              void* d_out, int out_size, void* d_ws, size_t ws_size,
                              hipStream_t stream) {
    const float* x1 = (const float*)d_in[0];
    const float* x2 = (const float*)d_in[1];
    const float* W1 = (const float*)d_in[2];
    const float* W2 = (const float*)d_in[3];
    const float* Wp = (const float*)d_in[4];
    const float* bp = (const float*)d_in[5];
    float* sbuf = (float*)d_ws;                                    // 8*16*512 floats = 256 KB
    unsigned short* Wt = (unsigned short*)((char*)d_ws + 262144);  // 1.5 MB

    w_tile<<<96, 256, 0, stream>>>(W1, W2, Wt);
    gemm_relu_rowsum<<<512, 256, 0, stream>>>(x1, x2, Wt, sbuf);
    proj_kernel<<<NB, 512, 0, stream>>>(sbuf, Wp, bp, (float*)d_out);
}